// Round 15
// baseline (245.048 us; speedup 1.0000x reference)
//
#include <hip/hip_runtime.h>

#define B 4
#define S 2048
#define D 768
#define H 8
#define DK 96
#define NBH (B*H)
#define SD (B*S*D)

typedef __bf16 bf16x8 __attribute__((ext_vector_type(8)));
typedef float f32x4 __attribute__((ext_vector_type(4)));
typedef unsigned short ushort_t;
typedef __attribute__((ext_vector_type(8))) unsigned short ushort8;
typedef __attribute__((ext_vector_type(4))) unsigned short us4;

static constexpr float NEG = -1.0e9f;
// 1/sqrt(96) * log2(e): folded into Q at projection; softmax in exp2 domain.
static constexpr float SCALE_L2E = 0.14724515567714155f;

__device__ __forceinline__ float exp2v(float x) { return __builtin_amdgcn_exp2f(x); }

__device__ __forceinline__ ushort_t f2bf(float f) {
    union { float f; unsigned u; } v; v.f = f;
    unsigned r = v.u + 0x7fffu + ((v.u >> 16) & 1u);
    return (ushort_t)(r >> 16);
}

__device__ __forceinline__ unsigned cvt_pk(float a, float b) {
    unsigned d;
    asm("v_cvt_pk_bf16_f32 %0, %1, %2" : "=v"(d) : "v"(a), "v"(b));
    return d;
}
__device__ __forceinline__ ushort8 pack8(const float4& a, const float4& b) {
    union { unsigned u[4]; ushort8 s; } r;
    r.u[0] = cvt_pk(a.x, a.y); r.u[1] = cvt_pk(a.z, a.w);
    r.u[2] = cvt_pk(b.x, b.y); r.u[3] = cvt_pk(b.z, b.w);
    return r.s;
}
__device__ __forceinline__ us4 pack4(const float4& a) {
    union { unsigned u[2]; us4 s; } r;
    r.u[0] = cvt_pk(a.x, a.y); r.u[1] = cvt_pk(a.z, a.w);
    return r.s;
}

#define MFMA16(a, b, c) __builtin_amdgcn_mfma_f32_16x16x32_bf16((a), (b), (c), 0, 0, 0)

// ---------------------------------------------------------------------------
// Kernel 0: fp32 -> bf16 conversion of W_q, W_v.
// ---------------------------------------------------------------------------
__global__ __launch_bounds__(256) void convert_bf16(
    const float* __restrict__ wq, const float* __restrict__ wv,
    ushort_t* __restrict__ wqb, ushort_t* __restrict__ wvb)
{
    const int stride = gridDim.x * 256;
    const int idx = blockIdx.x * 256 + threadIdx.x;
    for (int i = idx; i < (D * D) / 4; i += stride) {
        ((us4*)wqb)[i] = pack4(((const float4*)wq)[i]);
        ((us4*)wvb)[i] = pack4(((const float4*)wv)[i]);
    }
}

// ---------------------------------------------------------------------------
// Kernel 1: MFMA GEMM (R12 structure), double-buffered LDS + reg prefetch.
// Q = bf16((x@Wq^T + bq) * SCALE_L2E); KV = bf16(x@Wv^T + bv).
// z=1 additionally writes KVf: the V^T copy in MFMA-B-fragment-native order
//   KVf[((b*H+h)*6+df)*32768 + (s>>5)*512 + ((s>>3)&3)*128 + (d&15)*8 + (s&7)]
// so attn_pv's vf loads are fully coalesced per-wave 1KB reads.
// ---------------------------------------------------------------------------
__global__ __launch_bounds__(256) void in_proj_gemm(
    const float* __restrict__ x,
    const ushort_t* __restrict__ wqb, const float* __restrict__ bq,
    const ushort_t* __restrict__ wvb, const float* __restrict__ bv,
    ushort_t* __restrict__ Qb, ushort_t* __restrict__ KVb,
    ushort_t* __restrict__ KVf)
{
    const ushort_t* __restrict__ Wm = blockIdx.z ? wvb : wqb;
    const float* __restrict__ bia   = blockIdx.z ? bv : bq;
    ushort_t* __restrict__ outp     = blockIdx.z ? KVb : Qb;
    const float osc = blockIdx.z ? 1.0f : SCALE_L2E;

    const int bn = blockIdx.x * 128;
    const int bm = blockIdx.y * 128;
    const int tid = threadIdx.x;
    const int lane = tid & 63;
    const int wid = tid >> 6;
    const int wm = (wid >> 1) * 64, wn = (wid & 1) * 64;
    const int lr = lane & 15, lg = lane >> 4;

    __shared__ __align__(16) ushort_t As[2][128][40];
    __shared__ __align__(16) ushort_t Bs[2][128][40];

    const int r0 = tid >> 2, c8 = (tid & 3) * 8;
    const float*    xg0 = &x [(size_t)(bm + r0) * D + c8];
    const float*    xg1 = xg0 + (size_t)64 * D;
    const ushort_t* wg0 = &Wm[(size_t)(bn + r0) * D + c8];
    const ushort_t* wg1 = wg0 + (size_t)64 * D;

    float4 xv[4];
    ushort8 wv2[2];

    f32x4 acc[4][4];
    #pragma unroll
    for (int m = 0; m < 4; ++m)
        #pragma unroll
        for (int n = 0; n < 4; ++n) acc[m][n] = (f32x4){0.f, 0.f, 0.f, 0.f};

    {
        xv[0] = *(const float4*)(xg0);     xv[1] = *(const float4*)(xg0 + 4);
        xv[2] = *(const float4*)(xg1);     xv[3] = *(const float4*)(xg1 + 4);
        wv2[0] = *(const ushort8*)(wg0);   wv2[1] = *(const ushort8*)(wg1);
        *(ushort8*)&As[0][r0][c8]      = pack8(xv[0], xv[1]);
        *(ushort8*)&As[0][r0 + 64][c8] = pack8(xv[2], xv[3]);
        *(ushort8*)&Bs[0][r0][c8]      = wv2[0];
        *(ushort8*)&Bs[0][r0 + 64][c8] = wv2[1];
    }

    for (int k = 0; k < 24; ++k) {
        __syncthreads();
        const int buf = k & 1;
        if (k < 23) {
            const int ko = (k + 1) * 32;
            xv[0] = *(const float4*)(xg0 + ko);     xv[1] = *(const float4*)(xg0 + ko + 4);
            xv[2] = *(const float4*)(xg1 + ko);     xv[3] = *(const float4*)(xg1 + ko + 4);
            wv2[0] = *(const ushort8*)(wg0 + ko);   wv2[1] = *(const ushort8*)(wg1 + ko);
        }
        bf16x8 a[4], bfr[4];
        #pragma unroll
        for (int m = 0; m < 4; ++m) a[m]   = *(const bf16x8*)&As[buf][wm + m * 16 + lr][lg * 8];
        #pragma unroll
        for (int n = 0; n < 4; ++n) bfr[n] = *(const bf16x8*)&Bs[buf][wn + n * 16 + lr][lg * 8];
        __builtin_amdgcn_s_setprio(1);
        #pragma unroll
        for (int m = 0; m < 4; ++m)
            #pragma unroll
            for (int n = 0; n < 4; ++n)
                acc[m][n] = MFMA16(a[m], bfr[n], acc[m][n]);
        __builtin_amdgcn_s_setprio(0);
        if (k < 23) {
            const int nb = (k + 1) & 1;
            *(ushort8*)&As[nb][r0][c8]      = pack8(xv[0], xv[1]);
            *(ushort8*)&As[nb][r0 + 64][c8] = pack8(xv[2], xv[3]);
            *(ushort8*)&Bs[nb][r0][c8]      = wv2[0];
            *(ushort8*)&Bs[nb][r0 + 64][c8] = wv2[1];
        }
    }

    #pragma unroll
    for (int m = 0; m < 4; ++m) {
        #pragma unroll
        for (int n = 0; n < 4; ++n) {
            int col = bn + wn + n * 16 + lr;
            float bb = bia[col];
            int row0 = bm + wm + m * 16 + lg * 4;
            us4 o;
            #pragma unroll
            for (int r = 0; r < 4; ++r) o[r] = f2bf((acc[m][n][r] + bb) * osc);
            #pragma unroll
            for (int r = 0; r < 4; ++r) outp[(size_t)(row0 + r) * D + col] = o[r];
            if (blockIdx.z) {
                int hh = col / DK, dd = col - hh * DK;
                int df = dd >> 4, dd15 = dd & 15;
                int b2 = row0 >> 11, s = row0 & (S - 1);
                size_t off = ((size_t)(b2 * H + hh) * 6 + df) * 32768
                           + ((s >> 5) * 512 + ((s >> 3) & 3) * 128 + dd15 * 8 + (s & 7));
                *(us4*)&KVf[off] = o;
            }
        }
    }
}

// ---------------------------------------------------------------------------
// Kernel 2: column softmax stats (log2 domain). Wave owns 16 columns (K-frags
// in regs); online (m,s) lane-local. Q double-buffered in LDS, 1 sync/iter.
// Depth pairing: co-resident blocks (bh, bh+16) get jt and 31-jt.
// ---------------------------------------------------------------------------
__global__ __launch_bounds__(256) void col_stats(
    const ushort_t* __restrict__ Qb, const ushort_t* __restrict__ KVb,
    const int* __restrict__ amask,
    float* __restrict__ colM, float* __restrict__ colSinv)
{
    const int bh = blockIdx.y;
    const int jt = (bh & 16) ? (31 - (int)blockIdx.x) : (int)blockIdx.x;
    const int b = bh >> 3, h = bh & 7;
    const int j0 = jt * 64;
    const int tid = threadIdx.x;
    const int lane = tid & 63;
    const int w = tid >> 6;
    const int lr = lane & 15, lg = lane >> 4;

    __shared__ __align__(16) ushort_t qs[2][64][104];
    __shared__ int pads[2][64];

    bf16x8 kf[3];
    #pragma unroll
    for (int ks2 = 0; ks2 < 3; ++ks2)
        kf[ks2] = *(const bf16x8*)&KVb[(size_t)(b * S + j0 + w * 16 + lr) * D + h * DK + ks2 * 32 + lg * 8];

    int kr[3], kc[3];
    const ushort_t* qg[3];
    #pragma unroll
    for (int k3 = 0; k3 < 3; ++k3) {
        int c = tid + k3 * 256;
        kr[k3] = c / 12; kc[k3] = (c % 12) * 8;
        qg[k3] = &Qb[(size_t)(b * S + j0 + kr[k3]) * D + h * DK + kc[k3]];
    }
    const int* pg = amask + b * S + j0 + (tid < 64 ? tid : 0);

    ushort8 pq[3]; int ppad = 0;
    #pragma unroll
    for (int k3 = 0; k3 < 3; ++k3) { pq[k3] = *(const ushort8*)qg[k3]; qg[k3] += (size_t)64 * D; }
    if (tid < 64) { ppad = *pg; }
    pg += 64;

    float m = NEG, ssum = 0.f;
    const int jg = j0 + w * 16 + lr;
    const int nit = (S / 64) - jt;

    for (int t = 0; t < nit; ++t) {
        const int buf = t & 1;
        const int i0 = j0 + t * 64;
        #pragma unroll
        for (int k3 = 0; k3 < 3; ++k3) *(ushort8*)&qs[buf][kr[k3]][kc[k3]] = pq[k3];
        if (tid < 64) pads[buf][tid] = ppad;
        __syncthreads();
        if (t + 1 < nit) {
            #pragma unroll
            for (int k3 = 0; k3 < 3; ++k3) { pq[k3] = *(const ushort8*)qg[k3]; qg[k3] += (size_t)64 * D; }
            if (tid < 64) { ppad = *pg; }
            pg += 64;
        }

        f32x4 dacc[4];
        #pragma unroll
        for (int f = 0; f < 4; ++f) dacc[f] = (f32x4){0.f, 0.f, 0.f, 0.f};
        __builtin_amdgcn_s_setprio(1);
        #pragma unroll
        for (int ks2 = 0; ks2 < 3; ++ks2) {
            #pragma unroll
            for (int f = 0; f < 4; ++f) {
                bf16x8 afr = *(const bf16x8*)&qs[buf][f * 16 + lr][ks2 * 32 + lg * 8];
                dacc[f] = MFMA16(afr, kf[ks2], dacc[f]);
            }
        }
        __builtin_amdgcn_s_setprio(0);

        #pragma unroll
        for (int f = 0; f < 4; ++f) {
            const int ib = f * 16 + lg * 4;
            float wv[4];
            #pragma unroll
            for (int r = 0; r < 4; ++r) {
                int ig = i0 + ib + r;
                wv[r] = (pads[buf][ib + r] != 0 || jg > ig) ? NEG : dacc[f][r];
            }
            float vmax = fmaxf(fmaxf(wv[0], wv[1]), fmaxf(wv[2], wv[3]));
            float mn = fmaxf(m, vmax);
            ssum = ssum * exp2v(m - mn)
                 + exp2v(wv[0] - mn) + exp2v(wv[1] - mn)
                 + exp2v(wv[2] - mn) + exp2v(wv[3] - mn);
            m = mn;
        }
    }

    float m2 = m, s2 = ssum;
    #pragma unroll
    for (int off = 16; off < 64; off <<= 1) {
        float mo = __shfl_xor(m2, off);
        float so = __shfl_xor(s2, off);
        float mn = fmaxf(m2, mo);
        s2 = s2 * exp2v(m2 - mn) + so * exp2v(mo - mn);
        m2 = mn;
    }
    if (lane < 16) {
        if (m2 == NEG) s2 += (float)j0;  // skipped i<j0 rows: causal-masked, 2^0=1 each
        colM[bh * S + jg] = m2;
        colSinv[bh * S + jg] = 1.0f / s2;
    }
}

// ---------------------------------------------------------------------------
// Kernel 3: PV pass (log2 domain). K staged in LDS (reg prefetch); V read
// DIRECTLY from global KVf in fragment-native order (coalesced 1KB wave-loads,
// L1-shared across the block's 4 waves). kvt LDS eliminated: LDS/iter
// 136->76KB, footprint 40->23KB. Depth-paired grid; setprio on MFMA clusters.
// ---------------------------------------------------------------------------
__global__ __launch_bounds__(256, 4) void attn_pv(
    const ushort_t* __restrict__ Qb, const ushort_t* __restrict__ KVb,
    const ushort_t* __restrict__ KVf,
    const int* __restrict__ amask,
    const float* __restrict__ colM, const float* __restrict__ colSinv,
    const float* __restrict__ x, float* __restrict__ out)
{
    const int bh = blockIdx.y;
    const int it = (bh & 16) ? (31 - (int)blockIdx.x) : (int)blockIdx.x;
    const int b = bh >> 3, h = bh & 7;
    const int i0 = it * 64;
    const int tid = threadIdx.x;
    const int lane = tid & 63;
    const int w = tid >> 6;
    const int lr = lane & 15, lg = lane >> 4;

    __shared__ __align__(16) ushort_t kvs[64][104];  // rows = j (64), cols = d (96)
    __shared__ __align__(16) ushort_t ps[64][72];    // rows = i (64), cols = j (64)
    __shared__ __align__(16) float cm[64];
    __shared__ __align__(16) float csv[64];

    bf16x8 qf[3];
    #pragma unroll
    for (int ks2 = 0; ks2 < 3; ++ks2)
        qf[ks2] = *(const bf16x8*)&Qb[(size_t)(b * S + i0 + w * 16 + lr) * D + h * DK + ks2 * 32 + lg * 8];

    const int my_pad = (int)(amask[b * S + i0 + w * 16 + lr] != 0);
    const int i_g = i0 + w * 16 + lr;

    int kr[3], kc[3];
    const ushort_t* kvg[3];
    #pragma unroll
    for (int k3 = 0; k3 < 3; ++k3) {
        int c = tid + k3 * 256;
        kr[k3] = c / 12;  kc[k3] = (c % 12) * 8;
        kvg[k3] = &KVb[(size_t)(b * S + kr[k3]) * D + h * DK + kc[k3]];
    }
    // V fragment base (fragment-native layout): wave-load is lane-contiguous.
    const ushort_t* vg = KVf + (size_t)(b * H + h) * 6 * 32768 + (size_t)lane * 8;

    const float* cmg  = colM    + (size_t)bh * S + (tid < 64 ? tid : 0);
    const float* csvg = colSinv + (size_t)bh * S + (tid < 64 ? tid : 0);

    ushort8 pkv[3]; float pcm = 0.f, pcsv = 0.f;
    #pragma unroll
    for (int k3 = 0; k3 < 3; ++k3) {
        pkv[k3] = *(const ushort8*)kvg[k3];  kvg[k3] += (size_t)64 * D;
    }
    if (tid < 64) { pcm = *cmg; pcsv = *csvg; }
    cmg += 64; csvg += 64;

    f32x4 acc[6];
    #pragma unroll
    for (int df = 0; df < 6; ++df) acc[df] = (f32x4){0.f, 0.f, 0.f, 0.f};

    for (int jt2 = 0; jt2 <= it; ++jt2) {
        const int j0 = jt2 * 64;
        __syncthreads();                       // all waves done reading prev tile
        #pragma unroll
        for (int k3 = 0; k3 < 3; ++k3)
            *(ushort8*)&kvs[kr[k3]][kc[k3]] = pkv[k3];
        if (tid < 64) { cm[tid] = pcm; csv[tid] = pcsv; }
        __syncthreads();                       // staging visible
        if (jt2 < it) {                        // next-tile loads hide under compute
            #pragma unroll
            for (int k3 = 0; k3 < 3; ++k3) {
                pkv[k3] = *(const ushort8*)kvg[k3];  kvg[k3] += (size_t)64 * D;
            }
            if (tid < 64) { pcm = *cmg; pcsv = *csvg; }
            cmg += 64; csvg += 64;
        }

        // swapped QK^T: D[j-local = jf*16 + lg*4 + r][i = lr]
        f32x4 dacc[4];
        #pragma unroll
        for (int jf = 0; jf < 4; ++jf) dacc[jf] = (f32x4){0.f, 0.f, 0.f, 0.f};
        __builtin_amdgcn_s_setprio(1);
        #pragma unroll
        for (int ks2 = 0; ks2 < 3; ++ks2) {
            #pragma unroll
            for (int jf = 0; jf < 4; ++jf) {
                bf16x8 bfr = *(const bf16x8*)&kvs[jf * 16 + lr][ks2 * 32 + lg * 8];
                dacc[jf] = MFMA16(bfr, qf[ks2], dacc[jf]);
            }
        }
        __builtin_amdgcn_s_setprio(0);

        // mask + exp2 + normalize -> packed bf16 P (b64 writes, wave-private)
        #pragma unroll
        for (int jf = 0; jf < 4; ++jf) {
            const int jbase = jf * 16 + lg * 4;
            f32x4 cmv  = *(const f32x4*)&cm[jbase];
            f32x4 csvv = *(const f32x4*)&csv[jbase];
            float pv[4];
            #pragma unroll
            for (int r = 0; r < 4; ++r) {
                int jgl = j0 + jbase + r;
                bool msk = my_pad || (jgl > i_g);
                float wvv = msk ? NEG : dacc[jf][r];
                pv[r] = exp2v(wvv - cmv[r]) * csvv[r];
            }
            union { unsigned u[2]; uint2 v; } o;
            o.u[0] = cvt_pk(pv[0], pv[1]);
            o.u[1] = cvt_pk(pv[2], pv[3]);
            *(uint2*)&ps[w * 16 + lr][jbase] = o.v;
        }

        // PV: out[i][d] += P[i][j] * V^T[d][j]; V fragments from global KVf
        // (coalesced, L1-hot: all 4 waves read the same 12KB tile).
        const ushort_t* vit = vg + (size_t)jt2 * 1024;
        __builtin_amdgcn_s_setprio(1);
        #pragma unroll
        for (int ks2 = 0; ks2 < 2; ++ks2) {
            bf16x8 afr = *(const bf16x8*)&ps[w * 16 + lr][ks2 * 32 + lg * 8];
            #pragma unroll
            for (int df = 0; df < 6; ++df) {
                bf16x8 vfr = *(const bf16x8*)(vit + (size_t)df * 32768 + ks2 * 512);
                acc[df] = MFMA16(afr, vfr, acc[df]);
            }
        }
        __builtin_amdgcn_s_setprio(0);
    }

    #pragma unroll
    for (int df = 0; df < 6; ++df) {
        int d = h * DK + df * 16 + lr;
        #pragma unroll
        for (int r = 0; r < 4; ++r) {
            size_t gi = (size_t)(b * S + i0 + w * 16 + lg * 4 + r) * D + d;
            out[gi] = acc[df][r] + x[gi];
        }
    }
}

// ---------------------------------------------------------------------------
// Kernel 4: LayerNorm, one row per wave, shuffle reductions, no barriers.
// ---------------------------------------------------------------------------
__global__ __launch_bounds__(256) void layer_norm(
    float* __restrict__ out,
    const float* __restrict__ gamma, const float* __restrict__ beta)
{
    const int row = blockIdx.x * 4 + (threadIdx.x >> 6);
    const int lane = threadIdx.x & 63;
    float* o = out + (size_t)row * D;

    float4 v[3];
    #pragma unroll
    for (int p = 0; p < 3; ++p) v[p] = *(const float4*)&o[lane * 4 + p * 256];

    float s = 0.f;
    #pragma unroll
    for (int p = 0; p < 3; ++p) s += v[p].x + v[p].y + v[p].z + v[p].w;
    #pragma unroll
    for (int off = 1; off < 64; off <<= 1) s += __shfl_xor(s, off);
    const float mu = s * (1.0f / D);

    float q = 0.f;
    #pragma unroll
    for (int p = 0; p < 3; ++p) {
        float a = v[p].x - mu, bb = v[p].y - mu, c = v[p].z - mu, dd = v[p].w - mu;
        q += a * a + bb * bb + c * c + dd * dd;
    }
    #pragma unroll
    for (int off = 1; off < 64; off <<= 1) q += __shfl_xor(q, off);
    const float inv = 1.0f / sqrtf(q * (1.0f / D) + 1e-5f);

    #pragma unroll
    for (int p = 0; p < 3; ++p) {
        float4 g = *(const float4*)&gamma[lane * 4 + p * 256];
        float4 bt = *(const float4*)&beta[lane * 4 + p * 256];
        float4 r;
        r.x = (v[p].x - mu) * inv * g.x + bt.x;
        r.y = (v[p].y - mu) * inv * g.y + bt.y;
        r.z = (v[p].z - mu) * inv * g.z + bt.z;
        r.w = (v[p].w - mu) * inv * g.w + bt.w;
        *(float4*)&o[lane * 4 + p * 256] = r;
    }
}

// ---------------------------------------------------------------------------
extern "C" void kernel_launch(void* const* d_in, const int* in_sizes, int n_in,
                              void* d_out, int out_size, void* d_ws, size_t ws_size,
                              hipStream_t stream)
{
    const float* x     = (const float*)d_in[0];
    const int*   amask = (const int*)  d_in[1];
    const float* Wq    = (const float*)d_in[2];
    const float* bq    = (const float*)d_in[3];
    const float* Wv    = (const float*)d_in[4];
    const float* bv    = (const float*)d_in[5];
    const float* gamma = (const float*)d_in[6];
    const float* beta  = (const float*)d_in[7];
    float* out = (float*)d_out;

    ushort_t* wqb  = (ushort_t*)d_ws;
    ushort_t* wvb  = wqb + (size_t)D * D;
    ushort_t* Qb   = wvb + (size_t)D * D;
    ushort_t* KVb  = Qb  + (size_t)SD;
    ushort_t* KVf  = KVb + (size_t)SD;
    float* colM    = (float*)(KVf + (size_t)SD);
    float* colSinv = colM + (size_t)NBH * S;

    convert_bf16<<<576, 256, 0, stream>>>(Wq, Wv, wqb, wvb);
    in_proj_gemm<<<dim3(D / 128, (B * S) / 128, 2), 256, 0, stream>>>(
        x, wqb, bq, wvb, bv, Qb, KVb, KVf);
    col_stats<<<dim3(S / 64, NBH), 256, 0, stream>>>(
        Qb, KVb, amask, colM, colSinv);
    attn_pv<<<dim3(S / 64, NBH), 256, 0, stream>>>(
        Qb, KVb, KVf, amask, colM, colSinv, x, out);
    layer_norm<<<(B * S) / 4, 256, 0, stream>>>(out, gamma, beta);
}

// Round 16
// 158.424 us; speedup vs baseline: 1.5468x; 1.5468x over previous
//
#include <hip/hip_runtime.h>

#define B 4
#define S 2048
#define D 768
#define H 8
#define DK 96
#define NBH (B*H)
#define SD (B*S*D)

typedef __bf16 bf16x8 __attribute__((ext_vector_type(8)));
typedef float f32x4 __attribute__((ext_vector_type(4)));
typedef unsigned short ushort_t;
typedef __attribute__((ext_vector_type(8))) unsigned short ushort8;
typedef __attribute__((ext_vector_type(4))) unsigned short us4;

static constexpr float NEG = -1.0e9f;
// 1/sqrt(96) * log2(e): folded into Q at projection; softmax in exp2 domain.
static constexpr float SCALE_L2E = 0.14724515567714155f;

__device__ __forceinline__ float exp2v(float x) { return __builtin_amdgcn_exp2f(x); }

__device__ __forceinline__ ushort_t f2bf(float f) {
    union { float f; unsigned u; } v; v.f = f;
    unsigned r = v.u + 0x7fffu + ((v.u >> 16) & 1u);
    return (ushort_t)(r >> 16);
}

__device__ __forceinline__ unsigned cvt_pk(float a, float b) {
    unsigned d;
    asm("v_cvt_pk_bf16_f32 %0, %1, %2" : "=v"(d) : "v"(a), "v"(b));
    return d;
}
__device__ __forceinline__ ushort8 pack8(const float4& a, const float4& b) {
    union { unsigned u[4]; ushort8 s; } r;
    r.u[0] = cvt_pk(a.x, a.y); r.u[1] = cvt_pk(a.z, a.w);
    r.u[2] = cvt_pk(b.x, b.y); r.u[3] = cvt_pk(b.z, b.w);
    return r.s;
}
__device__ __forceinline__ us4 pack4(const float4& a) {
    union { unsigned u[2]; us4 s; } r;
    r.u[0] = cvt_pk(a.x, a.y); r.u[1] = cvt_pk(a.z, a.w);
    return r.s;
}

#define MFMA16(a, b, c) __builtin_amdgcn_mfma_f32_16x16x32_bf16((a), (b), (c), 0, 0, 0)

// ---------------------------------------------------------------------------
// Kernel 0: fp32 -> bf16 conversion of W_q, W_v.
// ---------------------------------------------------------------------------
__global__ __launch_bounds__(256) void convert_bf16(
    const float* __restrict__ wq, const float* __restrict__ wv,
    ushort_t* __restrict__ wqb, ushort_t* __restrict__ wvb)
{
    const int stride = gridDim.x * 256;
    const int idx = blockIdx.x * 256 + threadIdx.x;
    for (int i = idx; i < (D * D) / 4; i += stride) {
        ((us4*)wqb)[i] = pack4(((const float4*)wq)[i]);
        ((us4*)wvb)[i] = pack4(((const float4*)wv)[i]);
    }
}

// ---------------------------------------------------------------------------
// Kernel 1: MFMA GEMM (R12 exact), double-buffered LDS + reg prefetch.
// Q = bf16((x@Wq^T + bq) * SCALE_L2E); KV = bf16(x@Wv^T + bv); z=1 -> KVt too.
// ---------------------------------------------------------------------------
__global__ __launch_bounds__(256) void in_proj_gemm(
    const float* __restrict__ x,
    const ushort_t* __restrict__ wqb, const float* __restrict__ bq,
    const ushort_t* __restrict__ wvb, const float* __restrict__ bv,
    ushort_t* __restrict__ Qb, ushort_t* __restrict__ KVb,
    ushort_t* __restrict__ KVt)
{
    const ushort_t* __restrict__ Wm = blockIdx.z ? wvb : wqb;
    const float* __restrict__ bia   = blockIdx.z ? bv : bq;
    ushort_t* __restrict__ outp     = blockIdx.z ? KVb : Qb;
    const float osc = blockIdx.z ? 1.0f : SCALE_L2E;

    const int bn = blockIdx.x * 128;
    const int bm = blockIdx.y * 128;
    const int tid = threadIdx.x;
    const int lane = tid & 63;
    const int wid = tid >> 6;
    const int wm = (wid >> 1) * 64, wn = (wid & 1) * 64;
    const int lr = lane & 15, lg = lane >> 4;

    __shared__ __align__(16) ushort_t As[2][128][40];
    __shared__ __align__(16) ushort_t Bs[2][128][40];

    const int r0 = tid >> 2, c8 = (tid & 3) * 8;
    const float*    xg0 = &x [(size_t)(bm + r0) * D + c8];
    const float*    xg1 = xg0 + (size_t)64 * D;
    const ushort_t* wg0 = &Wm[(size_t)(bn + r0) * D + c8];
    const ushort_t* wg1 = wg0 + (size_t)64 * D;

    float4 xv[4];
    ushort8 wv2[2];

    f32x4 acc[4][4];
    #pragma unroll
    for (int m = 0; m < 4; ++m)
        #pragma unroll
        for (int n = 0; n < 4; ++n) acc[m][n] = (f32x4){0.f, 0.f, 0.f, 0.f};

    {
        xv[0] = *(const float4*)(xg0);     xv[1] = *(const float4*)(xg0 + 4);
        xv[2] = *(const float4*)(xg1);     xv[3] = *(const float4*)(xg1 + 4);
        wv2[0] = *(const ushort8*)(wg0);   wv2[1] = *(const ushort8*)(wg1);
        *(ushort8*)&As[0][r0][c8]      = pack8(xv[0], xv[1]);
        *(ushort8*)&As[0][r0 + 64][c8] = pack8(xv[2], xv[3]);
        *(ushort8*)&Bs[0][r0][c8]      = wv2[0];
        *(ushort8*)&Bs[0][r0 + 64][c8] = wv2[1];
    }

    for (int k = 0; k < 24; ++k) {
        __syncthreads();
        const int buf = k & 1;
        if (k < 23) {
            const int ko = (k + 1) * 32;
            xv[0] = *(const float4*)(xg0 + ko);     xv[1] = *(const float4*)(xg0 + ko + 4);
            xv[2] = *(const float4*)(xg1 + ko);     xv[3] = *(const float4*)(xg1 + ko + 4);
            wv2[0] = *(const ushort8*)(wg0 + ko);   wv2[1] = *(const ushort8*)(wg1 + ko);
        }
        bf16x8 a[4], bfr[4];
        #pragma unroll
        for (int m = 0; m < 4; ++m) a[m]   = *(const bf16x8*)&As[buf][wm + m * 16 + lr][lg * 8];
        #pragma unroll
        for (int n = 0; n < 4; ++n) bfr[n] = *(const bf16x8*)&Bs[buf][wn + n * 16 + lr][lg * 8];
        #pragma unroll
        for (int m = 0; m < 4; ++m)
            #pragma unroll
            for (int n = 0; n < 4; ++n)
                acc[m][n] = MFMA16(a[m], bfr[n], acc[m][n]);
        if (k < 23) {
            const int nb = (k + 1) & 1;
            *(ushort8*)&As[nb][r0][c8]      = pack8(xv[0], xv[1]);
            *(ushort8*)&As[nb][r0 + 64][c8] = pack8(xv[2], xv[3]);
            *(ushort8*)&Bs[nb][r0][c8]      = wv2[0];
            *(ushort8*)&Bs[nb][r0 + 64][c8] = wv2[1];
        }
    }

    #pragma unroll
    for (int m = 0; m < 4; ++m) {
        #pragma unroll
        for (int n = 0; n < 4; ++n) {
            int col = bn + wn + n * 16 + lr;
            float bb = bia[col];
            int row0 = bm + wm + m * 16 + lg * 4;
            us4 o;
            #pragma unroll
            for (int r = 0; r < 4; ++r) o[r] = f2bf((acc[m][n][r] + bb) * osc);
            #pragma unroll
            for (int r = 0; r < 4; ++r) outp[(size_t)(row0 + r) * D + col] = o[r];
            if (blockIdx.z) {
                int hh = col / DK, dd = col - hh * DK;
                int bb2 = row0 >> 11, ss = row0 & (S - 1);
                *(us4*)&KVt[((size_t)(bb2 * H + hh) * DK + dd) * S + ss] = o;
            }
        }
    }
}

// ---------------------------------------------------------------------------
// Kernel 2: column softmax stats (R12 exact; log2 domain, depth-paired).
// ---------------------------------------------------------------------------
__global__ __launch_bounds__(256) void col_stats(
    const ushort_t* __restrict__ Qb, const ushort_t* __restrict__ KVb,
    const int* __restrict__ amask,
    float* __restrict__ colM, float* __restrict__ colSinv)
{
    const int bh = blockIdx.y;
    const int jt = (bh & 16) ? (31 - (int)blockIdx.x) : (int)blockIdx.x;
    const int b = bh >> 3, h = bh & 7;
    const int j0 = jt * 64;
    const int tid = threadIdx.x;
    const int lane = tid & 63;
    const int w = tid >> 6;
    const int lr = lane & 15, lg = lane >> 4;

    __shared__ __align__(16) ushort_t qs[2][64][104];
    __shared__ int pads[2][64];

    bf16x8 kf[3];
    #pragma unroll
    for (int ks2 = 0; ks2 < 3; ++ks2)
        kf[ks2] = *(const bf16x8*)&KVb[(size_t)(b * S + j0 + w * 16 + lr) * D + h * DK + ks2 * 32 + lg * 8];

    int kr[3], kc[3];
    const ushort_t* qg[3];
    #pragma unroll
    for (int k3 = 0; k3 < 3; ++k3) {
        int c = tid + k3 * 256;
        kr[k3] = c / 12; kc[k3] = (c % 12) * 8;
        qg[k3] = &Qb[(size_t)(b * S + j0 + kr[k3]) * D + h * DK + kc[k3]];
    }
    const int* pg = amask + b * S + j0 + (tid < 64 ? tid : 0);

    ushort8 pq[3]; int ppad = 0;
    #pragma unroll
    for (int k3 = 0; k3 < 3; ++k3) { pq[k3] = *(const ushort8*)qg[k3]; qg[k3] += (size_t)64 * D; }
    if (tid < 64) { ppad = *pg; }
    pg += 64;

    float m = NEG, ssum = 0.f;
    const int jg = j0 + w * 16 + lr;
    const int nit = (S / 64) - jt;

    for (int t = 0; t < nit; ++t) {
        const int buf = t & 1;
        const int i0 = j0 + t * 64;
        #pragma unroll
        for (int k3 = 0; k3 < 3; ++k3) *(ushort8*)&qs[buf][kr[k3]][kc[k3]] = pq[k3];
        if (tid < 64) pads[buf][tid] = ppad;
        __syncthreads();
        if (t + 1 < nit) {
            #pragma unroll
            for (int k3 = 0; k3 < 3; ++k3) { pq[k3] = *(const ushort8*)qg[k3]; qg[k3] += (size_t)64 * D; }
            if (tid < 64) { ppad = *pg; }
            pg += 64;
        }

        f32x4 dacc[4];
        #pragma unroll
        for (int f = 0; f < 4; ++f) dacc[f] = (f32x4){0.f, 0.f, 0.f, 0.f};
        #pragma unroll
        for (int ks2 = 0; ks2 < 3; ++ks2) {
            #pragma unroll
            for (int f = 0; f < 4; ++f) {
                bf16x8 afr = *(const bf16x8*)&qs[buf][f * 16 + lr][ks2 * 32 + lg * 8];
                dacc[f] = MFMA16(afr, kf[ks2], dacc[f]);
            }
        }

        #pragma unroll
        for (int f = 0; f < 4; ++f) {
            const int ib = f * 16 + lg * 4;
            float wv[4];
            #pragma unroll
            for (int r = 0; r < 4; ++r) {
                int ig = i0 + ib + r;
                wv[r] = (pads[buf][ib + r] != 0 || jg > ig) ? NEG : dacc[f][r];
            }
            float vmax = fmaxf(fmaxf(wv[0], wv[1]), fmaxf(wv[2], wv[3]));
            float mn = fmaxf(m, vmax);
            ssum = ssum * exp2v(m - mn)
                 + exp2v(wv[0] - mn) + exp2v(wv[1] - mn)
                 + exp2v(wv[2] - mn) + exp2v(wv[3] - mn);
            m = mn;
        }
    }

    float m2 = m, s2 = ssum;
    #pragma unroll
    for (int off = 16; off < 64; off <<= 1) {
        float mo = __shfl_xor(m2, off);
        float so = __shfl_xor(s2, off);
        float mn = fmaxf(m2, mo);
        s2 = s2 * exp2v(m2 - mn) + so * exp2v(mo - mn);
        m2 = mn;
    }
    if (lane < 16) {
        if (m2 == NEG) s2 += (float)j0;  // skipped i<j0 rows: causal-masked, 2^0=1 each
        colM[bh * S + jg] = m2;
        colSinv[bh * S + jg] = 1.0f / s2;
    }
}

// ---------------------------------------------------------------------------
// Kernel 3: PV pass (log2 domain). 8 waves / 128 rows per block: each staged
// K/V tile + each barrier serves 2x the rows of R12, with UNCHANGED per-thread
// register state (each wave still owns 16 rows). Depth pairing (it, 15-it).
// LDS 48KB -> 2 blocks/CU.
// ---------------------------------------------------------------------------
__global__ __launch_bounds__(512, 4) void attn_pv(
    const ushort_t* __restrict__ Qb, const ushort_t* __restrict__ KVb,
    const ushort_t* __restrict__ KVt,
    const int* __restrict__ amask,
    const float* __restrict__ colM, const float* __restrict__ colSinv,
    const float* __restrict__ x, float* __restrict__ out)
{
    const int bh = blockIdx.y;
    const int it = (bh & 16) ? (15 - (int)blockIdx.x) : (int)blockIdx.x;
    const int b = bh >> 3, h = bh & 7;
    const int i0 = it * 128;
    const int tid = threadIdx.x;
    const int lane = tid & 63;
    const int w = tid >> 6;                    // 0..7
    const int lr = lane & 15, lg = lane >> 4;

    __shared__ __align__(16) ushort_t kvs[64][104];  // rows = j (64), cols = d (96)
    __shared__ __align__(16) ushort_t kvt[96][88];   // rows = d (96), cols = j (64)
    __shared__ __align__(16) ushort_t ps[128][72];   // rows = i (128), cols = j (64)
    __shared__ __align__(16) float cm[64];
    __shared__ __align__(16) float csv[64];

    // Q fragments: wave w owns rows i0 + w*16 .. +15 (same per-wave shape as R12)
    bf16x8 qf[3];
    #pragma unroll
    for (int ks2 = 0; ks2 < 3; ++ks2)
        qf[ks2] = *(const bf16x8*)&Qb[(size_t)(b * S + i0 + w * 16 + lr) * D + h * DK + ks2 * 32 + lg * 8];

    const int my_pad = (int)(amask[b * S + i0 + w * 16 + lr] != 0);
    const int i_g = i0 + w * 16 + lr;

    // staging: 1536 ushort8-chunks (768 kvs + 768 kvt) over 512 threads x 3
    ushort_t* ldst[3];
    const ushort_t* gsrc[3];
    size_t gstr[3];
    #pragma unroll
    for (int k3 = 0; k3 < 3; ++k3) {
        int c = tid + k3 * 512;
        if (c < 768) {
            int r = c / 12, cc = (c % 12) * 8;
            ldst[k3] = &kvs[r][cc];
            gsrc[k3] = &KVb[(size_t)(b * S + r) * D + h * DK + cc];
            gstr[k3] = (size_t)64 * D;
        } else {
            int c2 = c - 768;
            int r = c2 >> 3, cc = (c2 & 7) * 8;
            ldst[k3] = &kvt[r][cc];
            gsrc[k3] = &KVt[((size_t)(b * H + h) * DK + r) * S + cc];
            gstr[k3] = 64;
        }
    }
    const float* cmg  = colM    + (size_t)bh * S + (tid < 64 ? tid : 0);
    const float* csvg = colSinv + (size_t)bh * S + (tid < 64 ? tid : 0);

    ushort8 pk[3]; float pcm = 0.f, pcsv = 0.f;
    #pragma unroll
    for (int k3 = 0; k3 < 3; ++k3) { pk[k3] = *(const ushort8*)gsrc[k3]; gsrc[k3] += gstr[k3]; }
    if (tid < 64) { pcm = *cmg; pcsv = *csvg; }
    cmg += 64; csvg += 64;

    f32x4 acc[6];
    #pragma unroll
    for (int df = 0; df < 6; ++df) acc[df] = (f32x4){0.f, 0.f, 0.f, 0.f};

    const int nj = 2 * it + 2;
    for (int jt2 = 0; jt2 < nj; ++jt2) {
        const int j0 = jt2 * 64;
        __syncthreads();                       // all waves done reading prev tile
        #pragma unroll
        for (int k3 = 0; k3 < 3; ++k3)
            *(ushort8*)ldst[k3] = pk[k3];
        if (tid < 64) { cm[tid] = pcm; csv[tid] = pcsv; }
        __syncthreads();                       // staging visible
        if (jt2 + 1 < nj) {                    // next-tile loads hide under compute
            #pragma unroll
            for (int k3 = 0; k3 < 3; ++k3) { pk[k3] = *(const ushort8*)gsrc[k3]; gsrc[k3] += gstr[k3]; }
            if (tid < 64) { pcm = *cmg; pcsv = *csvg; }
            cmg += 64; csvg += 64;
        }

        // swapped QK^T: D[j-local = jf*16 + lg*4 + r][i = lr]
        f32x4 dacc[4];
        #pragma unroll
        for (int jf = 0; jf < 4; ++jf) dacc[jf] = (f32x4){0.f, 0.f, 0.f, 0.f};
        #pragma unroll
        for (int ks2 = 0; ks2 < 3; ++ks2) {
            #pragma unroll
            for (int jf = 0; jf < 4; ++jf) {
                bf16x8 bfr = *(const bf16x8*)&kvs[jf * 16 + lr][ks2 * 32 + lg * 8];
                dacc[jf] = MFMA16(bfr, qf[ks2], dacc[jf]);
            }
        }

        // mask + exp2 + normalize -> packed bf16 P (b64 writes, wave-private)
        #pragma unroll
        for (int jf = 0; jf < 4; ++jf) {
            const int jbase = jf * 16 + lg * 4;
            f32x4 cmv  = *(const f32x4*)&cm[jbase];
            f32x4 csvv = *(const f32x4*)&csv[jbase];
            float pv[4];
            #pragma unroll
            for (int r = 0; r < 4; ++r) {
                int jgl = j0 + jbase + r;
                bool msk = my_pad || (jgl > i_g);
                float wvv = msk ? NEG : dacc[jf][r];
                pv[r] = exp2v(wvv - cmv[r]) * csvv[r];
            }
            union { unsigned u[2]; uint2 v; } o;
            o.u[0] = cvt_pk(pv[0], pv[1]);
            o.u[1] = cvt_pk(pv[2], pv[3]);
            *(uint2*)&ps[w * 16 + lr][jbase] = o.v;
        }

        // PV: out[i][d] += P[i][j] * V^T[d][j]   (ps rows wave-private)
        #pragma unroll
        for (int ks2 = 0; ks2 < 2; ++ks2) {
            bf16x8 afr = *(const bf16x8*)&ps[w * 16 + lr][ks2 * 32 + lg * 8];
            #pragma unroll
            for (int df = 0; df < 6; ++df) {
                bf16x8 bfr = *(const bf16x8*)&kvt[df * 16 + lr][ks2 * 32 + lg * 8];
                acc[df] = MFMA16(afr, bfr, acc[df]);
            }
        }
    }

    #pragma unroll
    for (int df = 0; df < 6; ++df) {
        int d = h * DK + df * 16 + lr;
        #pragma unroll
        for (int r = 0; r < 4; ++r) {
            size_t gi = (size_t)(b * S + i0 + w * 16 + lg * 4 + r) * D + d;
            out[gi] = acc[df][r] + x[gi];
        }
    }
}

// ---------------------------------------------------------------------------
// Kernel 4: LayerNorm, one row per wave, shuffle reductions, no barriers.
// ---------------------------------------------------------------------------
__global__ __launch_bounds__(256) void layer_norm(
    float* __restrict__ out,
    const float* __restrict__ gamma, const float* __restrict__ beta)
{
    const int row = blockIdx.x * 4 + (threadIdx.x >> 6);
    const int lane = threadIdx.x & 63;
    float* o = out + (size_t)row * D;

    float4 v[3];
    #pragma unroll
    for (int p = 0; p < 3; ++p) v[p] = *(const float4*)&o[lane * 4 + p * 256];

    float s = 0.f;
    #pragma unroll
    for (int p = 0; p < 3; ++p) s += v[p].x + v[p].y + v[p].z + v[p].w;
    #pragma unroll
    for (int off = 1; off < 64; off <<= 1) s += __shfl_xor(s, off);
    const float mu = s * (1.0f / D);

    float q = 0.f;
    #pragma unroll
    for (int p = 0; p < 3; ++p) {
        float a = v[p].x - mu, bb = v[p].y - mu, c = v[p].z - mu, dd = v[p].w - mu;
        q += a * a + bb * bb + c * c + dd * dd;
    }
    #pragma unroll
    for (int off = 1; off < 64; off <<= 1) q += __shfl_xor(q, off);
    const float inv = 1.0f / sqrtf(q * (1.0f / D) + 1e-5f);

    #pragma unroll
    for (int p = 0; p < 3; ++p) {
        float4 g = *(const float4*)&gamma[lane * 4 + p * 256];
        float4 bt = *(const float4*)&beta[lane * 4 + p * 256];
        float4 r;
        r.x = (v[p].x - mu) * inv * g.x + bt.x;
        r.y = (v[p].y - mu) * inv * g.y + bt.y;
        r.z = (v[p].z - mu) * inv * g.z + bt.z;
        r.w = (v[p].w - mu) * inv * g.w + bt.w;
        *(float4*)&o[lane * 4 + p * 256] = r;
    }
}

// ---------------------------------------------------------------------------
extern "C" void kernel_launch(void* const* d_in, const int* in_sizes, int n_in,
                              void* d_out, int out_size, void* d_ws, size_t ws_size,
                              hipStream_t stream)
{
    const float* x     = (const float*)d_in[0];
    const int*   amask = (const int*)  d_in[1];
    const float* Wq    = (const float*)d_in[2];
    const float* bq    = (const float*)d_in[3];
    const float* Wv    = (const float*)d_in[4];
    const float* bv    = (const float*)d_in[5];
    const float* gamma = (const float*)d_in[6];
    const float* beta  = (const float*)d_in[7];
    float* out = (float*)d_out;

    ushort_t* wqb  = (ushort_t*)d_ws;
    ushort_t* wvb  = wqb + (size_t)D * D;
    ushort_t* Qb   = wvb + (size_t)D * D;
    ushort_t* KVb  = Qb  + (size_t)SD;
    ushort_t* KVt  = KVb + (size_t)SD;
    float* colM    = (float*)(KVt + (size_t)SD);
    float* colSinv = colM + (size_t)NBH * S;

    convert_bf16<<<576, 256, 0, stream>>>(Wq, Wv, wqb, wvb);
    in_proj_gemm<<<dim3(D / 128, (B * S) / 128, 2), 256, 0, stream>>>(
        x, wqb, bq, wvb, bv, Qb, KVb, KVt);
    col_stats<<<dim3(S / 64, NBH), 256, 0, stream>>>(
        Qb, KVb, amask, colM, colSinv);
    attn_pv<<<dim3(16, 32), 512, 0, stream>>>(
        Qb, KVb, KVt, amask, colM, colSinv, x, out);
    layer_norm<<<(B * S) / 4, 256, 0, stream>>>(out, gamma, beta);
}